// Round 7
// baseline (163.873 us; speedup 1.0000x reference)
//
#include <hip/hip_runtime.h>

// ---------------------------------------------------------------------------
// Types / helpers
// ---------------------------------------------------------------------------
typedef __attribute__((ext_vector_type(8))) short bf16x8;   // 8 bf16 = 4 VGPR
typedef __attribute__((ext_vector_type(4))) short bf16x4;   // 8 bytes
typedef __attribute__((ext_vector_type(4))) float f32x4;    // MFMA acc

static __device__ __forceinline__ short f2bf(float f) {      // RNE
    union { float f; unsigned u; } v; v.f = f;
    unsigned r = v.u + 0x7fffu + ((v.u >> 16) & 1u);
    return (short)(r >> 16);
}

// raw v_exp_f32: computes 2^x in one VALU op (libm exp2f = slow OCML path)
static __device__ __forceinline__ float exp2_fast(float x) {
    float r; asm("v_exp_f32 %0, %1" : "=v"(r) : "v"(x)); return r;
}

// async global->LDS, 16B per lane; lds dest MUST be base + lane*16 (m97/m104)
static __device__ __forceinline__ void async_copy16(const short* g, short* l) {
    __builtin_amdgcn_global_load_lds((const __attribute__((address_space(1))) void*)g,
                                     (__attribute__((address_space(3))) void*)l,
                                     16, 0, 0);
}

// raw barrier (no implicit vmcnt drain) + compile-time motion fences
#define BARX()                                            \
    do {                                                  \
        asm volatile("" ::: "memory");                    \
        __builtin_amdgcn_s_barrier();                     \
        __builtin_amdgcn_sched_barrier(0);                \
    } while (0)

#define HEADS 16
#define DHEAD 64
#define NSEQ  2048
#define DIM   1024
#define BATCH 2
#define ROWS  (BATCH * NSEQ)          // 4096
#define NQKV  (3 * HEADS * DHEAD)     // 3072

// q scale folded with log2(e): attn uses exp2 directly.  0.125 * log2(e)
#define QSCALE 0.18033688f

// ---------------------------------------------------------------------------
// Prep megakernel (unchanged) — one dispatch, roles by block range:
//   [0,768):      w_qkv [1024][3072] -> wqkvT [3072][1024]  (64x64 tiles)
//   [768,1024):   w_out [1024][1024] -> woutT [1024][1024]  (64x64 tiles)
//   [1024,5120):  rmsnorm row (blk-1024)
// ---------------------------------------------------------------------------
__global__ __launch_bounds__(256) void prep_kernel(const float* __restrict__ x,
                                                   const float* __restrict__ gamma,
                                                   const float* __restrict__ w_qkv,
                                                   const float* __restrict__ w_out,
                                                   short* __restrict__ xn,
                                                   short* __restrict__ wqkvT,
                                                   short* __restrict__ woutT) {
    const int blk = blockIdx.x;
    const int t = threadIdx.x;
    __shared__ float tile[64][65];
    __shared__ float part[4];

    if (blk < 1024) {
        // ---- transpose+cast role (64x64 tile) ----
        const float* in;  short* out;  int C, bx, by;
        if (blk < 768) { in = w_qkv; out = wqkvT; C = NQKV; bx = blk % 48; by = blk / 48; }
        else           { in = w_out; out = woutT; C = DIM;  bx = (blk - 768) & 15; by = (blk - 768) >> 4; }
        const int gx = bx * 64, gy = by * 64;
        const int lc4 = (t & 15) * 4;          // load col 0..60
        const int lr  = t >> 4;                // load row 0..15 (x4 passes)
#pragma unroll
        for (int p = 0; p < 4; ++p) {
            const float4 v = *(const float4*)&in[(size_t)(gy + p * 16 + lr) * C + gx + lc4];
            tile[p * 16 + lr][lc4 + 0] = v.x;
            tile[p * 16 + lr][lc4 + 1] = v.y;
            tile[p * 16 + lr][lc4 + 2] = v.z;
            tile[p * 16 + lr][lc4 + 3] = v.w;
        }
        __syncthreads();
        const int oc  = t >> 2;                // output row 0..63 (input col)
        const int or4 = (t & 3) * 16;          // 16 output elems per thread
#pragma unroll
        for (int j = 0; j < 4; ++j) {
            bf16x4 w;
#pragma unroll
            for (int r = 0; r < 4; ++r) w[r] = f2bf(tile[or4 + j * 4 + r][oc]);
            *(bf16x4*)&out[(size_t)(gx + oc) * DIM + gy + or4 + j * 4] = w;
        }
    } else {
        // ---- rmsnorm role ----
        const int row = blk - 1024;
        const float4 v = ((const float4*)(x + (size_t)row * DIM))[t];
        float s = v.x * v.x + v.y * v.y + v.z * v.z + v.w * v.w;
#pragma unroll
        for (int off = 32; off > 0; off >>= 1) s += __shfl_down(s, off, 64);
        if ((t & 63) == 0) part[t >> 6] = s;
        __syncthreads();
        const float tot = part[0] + part[1] + part[2] + part[3];
        const float scale = 32.0f / fmaxf(sqrtf(tot), 1e-12f);   // sqrt(1024)=32
        const float4 g = ((const float4*)gamma)[t];
        bf16x4 o;
        o[0] = f2bf(v.x * scale * g.x);
        o[1] = f2bf(v.y * scale * g.y);
        o[2] = f2bf(v.z * scale * g.z);
        o[3] = f2bf(v.w * scale * g.w);
        *(bf16x4*)(xn + (size_t)row * DIM + t * 4) = o;
    }
}

// ---------------------------------------------------------------------------
// QKV GEMM v3: counted-vmcnt 2-deep pipeline (T4, m218 mechanism).
//   tile 256x192, BK=64, 8 waves; 2 LDS bufs but TWO tiles of loads in
//   flight: per K-tile {22 ds_read + 48 MFMA on buf c} -> lgkm0+bar (c free)
//   -> stage tile t+2 into c -> vmcnt(7) (t+1's 7 loads done, t+2's 7 stay
//   outstanding) -> bar.  Loads get a full tile-time to land; 2 barriers/tile.
//   XOR swizzle col ^ (row&7)*8 (linear gload_lds dest, pre-swz source).
// Epilogue: q/k scatter (q scaled QSCALE); V transposed to vt [b*h][d][n].
// ---------------------------------------------------------------------------
__global__ __launch_bounds__(512, 2) void gemm_qkv(const short* __restrict__ A,
                                                   const short* __restrict__ Bt,
                                                   short* __restrict__ qkOut,
                                                   short* __restrict__ vtOut) {
    __shared__ alignas(16) short lA[2][256 * 64];   // 64 KB
    __shared__ alignas(16) short lB[2][192 * 64];   // 48 KB
    const int tid = threadIdx.x;
    const int lane = tid & 63, wid = tid >> 6;
    const int quad = lane >> 4, l16 = lane & 15;
    const int wm = wid >> 2, wn = wid & 3;          // 2M x 4N waves

    int flat = blockIdx.x;
    flat = (flat & 7) * 32 + (flat >> 3);           // XCD chunk swizzle
    const int mb = (flat >> 4) * 256;
    const int nb = (flat & 15) * 192;

    f32x4 acc[8][3];
#pragma unroll
    for (int i = 0; i < 8; ++i)
#pragma unroll
        for (int j = 0; j < 3; ++j) acc[i][j] = (f32x4){0.f, 0.f, 0.f, 0.f};

    // staging: 512 thr x 16B = 64 rows x 128B per load; source col pre-swizzled
    const int srow = tid >> 3;                 // 0..63
    const int scol = (tid & 7) * 8;            // linear LDS col (shorts)
    const int scolx = scol ^ ((srow & 7) * 8); // swizzled global col

    auto stageA = [&](int kb, int buf) {
#pragma unroll
        for (int c = 0; c < 4; ++c) {
            const int row = c * 64 + srow;
            async_copy16(&A[(size_t)(mb + row) * 1024 + kb + scolx],
                         &lA[buf][row * 64 + scol]);
        }
    };
    auto stageB = [&](int kb, int buf) {
#pragma unroll
        for (int c = 0; c < 3; ++c) {
            const int row = c * 64 + srow;
            async_copy16(&Bt[(size_t)(nb + row) * 1024 + kb + scolx],
                         &lB[buf][row * 64 + scol]);
        }
    };
    // swizzled fragment reads (2-way banked = free)
    auto rdA = [&](int buf, int mt, int kh) -> bf16x8 {
        const int row = wm * 128 + mt * 16 + l16;
        const int col = (kh * 32 + quad * 8) ^ ((row & 7) * 8);
        return *(const bf16x8*)&lA[buf][row * 64 + col];
    };
    auto rdB = [&](int buf, int nt, int kh) -> bf16x8 {
        const int row = wn * 48 + nt * 16 + l16;
        const int col = (kh * 32 + quad * 8) ^ ((row & 7) * 8);
        return *(const bf16x8*)&lB[buf][row * 64 + col];
    };

    // prologue: tiles 0 and 1 in flight; gate on tile 0 (oldest 7 of 14)
    stageA(0, 0);
    stageB(0, 0);
    stageA(64, 1);
    stageB(64, 1);
    asm volatile("s_waitcnt vmcnt(7)" ::: "memory");
    BARX();

    int cur = 0;
    for (int kt = 0; kt < 16; ++kt) {
        // ---- compute tile kt on buf cur (reads staggered; MFMA clustered) ----
        bf16x8 a[4][2], b01[2][2], b2[2];
#pragma unroll
        for (int mt = 0; mt < 4; ++mt)
#pragma unroll
            for (int kh = 0; kh < 2; ++kh) a[mt][kh] = rdA(cur, mt, kh);
#pragma unroll
        for (int nt = 0; nt < 2; ++nt)
#pragma unroll
            for (int kh = 0; kh < 2; ++kh) b01[nt][kh] = rdB(cur, nt, kh);
        __builtin_amdgcn_s_setprio(1);
#pragma unroll
        for (int kh = 0; kh < 2; ++kh)
#pragma unroll
            for (int mt = 0; mt < 4; ++mt)
#pragma unroll
                for (int nt = 0; nt < 2; ++nt)
                    acc[mt][nt] = __builtin_amdgcn_mfma_f32_16x16x32_bf16(
                        a[mt][kh], b01[nt][kh], acc[mt][nt], 0, 0, 0);
        __builtin_amdgcn_s_setprio(0);
#pragma unroll
        for (int kh = 0; kh < 2; ++kh) b2[kh] = rdB(cur, 2, kh);
        __builtin_amdgcn_s_setprio(1);
#pragma unroll
        for (int kh = 0; kh < 2; ++kh)
#pragma unroll
            for (int mt = 0; mt < 4; ++mt)
                acc[mt][2] = __builtin_amdgcn_mfma_f32_16x16x32_bf16(
                    a[mt][kh], b2[kh], acc[mt][2], 0, 0, 0);
        __builtin_amdgcn_s_setprio(0);
#pragma unroll
        for (int mt = 0; mt < 4; ++mt)
#pragma unroll
            for (int kh = 0; kh < 2; ++kh) a[mt][kh] = rdA(cur, mt + 4, kh);
        __builtin_amdgcn_s_setprio(1);
#pragma unroll
        for (int kh = 0; kh < 2; ++kh)
#pragma unroll
            for (int mt = 0; mt < 4; ++mt) {
                acc[mt + 4][2] = __builtin_amdgcn_mfma_f32_16x16x32_bf16(
                    a[mt][kh], b2[kh], acc[mt + 4][2], 0, 0, 0);
#pragma unroll
                for (int nt = 0; nt < 2; ++nt)
                    acc[mt + 4][nt] = __builtin_amdgcn_mfma_f32_16x16x32_bf16(
                        a[mt][kh], b01[nt][kh], acc[mt + 4][nt], 0, 0, 0);
            }
        __builtin_amdgcn_s_setprio(0);

        // ---- barrier 1: buf cur fully read by all waves ----
        asm volatile("s_waitcnt lgkmcnt(0)" ::: "memory");
        BARX();
        // ---- stage tile kt+2 into just-freed buf; gate tile kt+1 ----
        if (kt + 2 < 16) {
            stageA((kt + 2) * 64, cur);
            stageB((kt + 2) * 64, cur);
            asm volatile("s_waitcnt vmcnt(7)" ::: "memory");
        } else {
            asm volatile("s_waitcnt vmcnt(0)" ::: "memory");
        }
        BARX();
        cur ^= 1;
    }

    // ---- epilogue: q/k scatter + transposed V ----
#pragma unroll
    for (int mt = 0; mt < 8; ++mt) {
#pragma unroll
        for (int nt = 0; nt < 3; ++nt) {
            const int grow0 = mb + wm * 128 + mt * 16 + quad * 4;
            const int gcol  = nb + wn * 48 + nt * 16 + l16;
            const int s3 = gcol >> 10, rem = gcol & 1023;
            const int hh = rem >> 6, dd = rem & 63;
            const int bb = grow0 >> 11, npos0 = grow0 & 2047;
            if (s3 == 2) {
                bf16x4 vw;
#pragma unroll
                for (int r = 0; r < 4; ++r) vw[r] = f2bf(acc[mt][nt][r]);
                *(bf16x4*)&vtOut[((size_t)(bb * 16 + hh) * 64 + dd) * 2048 + npos0] = vw;
            } else {
                const float sc = (s3 == 0) ? QSCALE : 1.0f;
#pragma unroll
                for (int r = 0; r < 4; ++r)
                    qkOut[(size_t)((s3 * 32 + bb * 16 + hh) * 2048 + npos0 + r) * 64 + dd] =
                        f2bf(acc[mt][nt][r] * sc);
            }
        }
    }
}

// ---------------------------------------------------------------------------
// Output GEMM (unchanged from round 5): BK=64, XOR-swizzled, 2-phase.
// ---------------------------------------------------------------------------
__global__ __launch_bounds__(256, 3) void gemm_out(const short* __restrict__ A,
                                                   const short* __restrict__ Bt,
                                                   float* __restrict__ Cout) {
    __shared__ alignas(16) short lA2[2][128 * 64];   // 32 KB
    __shared__ alignas(16) short lB2[2][64 * 64];    // 16 KB
    const int tid = threadIdx.x;
    const int lane = tid & 63, wid = tid >> 6;
    const int quad = lane >> 4, l16 = lane & 15;

    const int nx = 16;                 // N blocks
    int flat = blockIdx.y * nx + blockIdx.x;
    flat = (flat & 7) * 64 + (flat >> 3);            // XCD swizzle (512/8=64)
    const int mb = (flat / nx) * 128, nb = (flat % nx) * 64;

    f32x4 acc[2][4];
#pragma unroll
    for (int i = 0; i < 2; ++i)
#pragma unroll
        for (int j = 0; j < 4; ++j) acc[i][j] = (f32x4){0.f, 0.f, 0.f, 0.f};

    auto stage = [&](int kb, int buf) {
#pragma unroll
        for (int p = 0; p < 4; ++p) {               // A: 128 rows x 8 slots
            const int ck = p * 256 + tid;
            const int ar = ck >> 3, as_ = ck & 7;
            async_copy16(&A[(size_t)(mb + ar) * 1024 + kb + ((as_ ^ (ar & 7)) * 8)],
                         &lA2[buf][ck * 8]);
        }
#pragma unroll
        for (int p = 0; p < 2; ++p) {               // B: 64 rows x 8 slots
            const int cb = p * 256 + tid;
            const int br = cb >> 3, bs = cb & 7;
            async_copy16(&Bt[(size_t)(nb + br) * 1024 + kb + ((bs ^ (br & 7)) * 8)],
                         &lB2[buf][cb * 8]);
        }
    };

    stage(0, 0);
    __syncthreads();

    int cur = 0;
    for (int kt = 0; kt < 16; ++kt) {
        if (kt + 1 < 16) stage((kt + 1) * 64, cur ^ 1);

        bf16x8 af[2][2], bfr[4][2];
#pragma unroll
        for (int mt = 0; mt < 2; ++mt) {
            const int row = wid * 32 + mt * 16 + l16;
#pragma unroll
            for (int kh = 0; kh < 2; ++kh)
                af[mt][kh] = *(const bf16x8*)&lA2[cur][row * 64 +
                                                      (((kh * 4 + quad) ^ (row & 7)) * 8)];
        }
#pragma unroll
        for (int nt = 0; nt < 4; ++nt) {
            const int row = nt * 16 + l16;
#pragma unroll
            for (int kh = 0; kh < 2; ++kh)
                bfr[nt][kh] = *(const bf16x8*)&lB2[cur][row * 64 +
                                                       (((kh * 4 + quad) ^ (row & 7)) * 8)];
        }
#pragma unroll
        for (int kh = 0; kh < 2; ++kh)
#pragma unroll
            for (int mt = 0; mt < 2; ++mt)
#pragma unroll
                for (int nt = 0; nt < 4; ++nt)
                    acc[mt][nt] = __builtin_amdgcn_mfma_f32_16x16x32_bf16(
                        af[mt][kh], bfr[nt][kh], acc[mt][nt], 0, 0, 0);
        __syncthreads();
        cur ^= 1;
    }

#pragma unroll
    for (int mt = 0; mt < 2; ++mt) {
#pragma unroll
        for (int nt = 0; nt < 4; ++nt) {
            const int grow0 = mb + wid * 32 + mt * 16 + quad * 4;
            const int gcol  = nb + nt * 16 + l16;
#pragma unroll
            for (int r = 0; r < 4; ++r)
                Cout[(size_t)(grow0 + r) * DIM + gcol] = acc[mt][nt][r];
        }
    }
}

// ---------------------------------------------------------------------------
// Causal flash attention v7 (unchanged from round 5): KVBLK=128 per step.
// ---------------------------------------------------------------------------
__global__ __launch_bounds__(256, 2) void attn_kernel(const short* __restrict__ qg,
                                                      const short* __restrict__ kg,
                                                      const short* __restrict__ vtg,
                                                      short* __restrict__ og) {
    const int tid = threadIdx.x;
    const int wid = tid >> 6, lane = tid & 63;
    const int quad = lane >> 4, l16 = lane & 15;
    const int blk = blockIdx.x;                 // 0..511
    // balanced pairing: qt(c) + qt(c+256) = 15 for all c
    const int qt = (blk < 256) ? (15 - (blk >> 5)) : ((blk - 256) >> 5);
    const int bh = blk & 31;
    const size_t base = (size_t)bh * (NSEQ * DHEAD);
    const int bb = bh >> 4, hh = bh & 15;
    const int qbase = qt * 128 + wid * 32;      // this wave's first query
    const int steps = qt + 1;                   // 128-key steps

    __shared__ alignas(16) short kT[2][128 * 64];   // 16 KB each buf
    __shared__ alignas(16) short vT[2][64 * 128];   // 16 KB each buf

    auto stage = [&](int s, int buf) {
        const int kb = s * 128;
#pragma unroll
        for (int p = 0; p < 4; ++p) {               // K: 128 rows x 8 slots
            const int ck = p * 256 + tid;
            const int kr = ck >> 3, ksl = ck & 7;
            async_copy16(&kg[base + (size_t)(kb + kr) * 64 + ((ksl ^ (kr & 7)) * 8)],
                         &kT[buf][ck * 8]);
        }
#pragma unroll
        for (int p = 0; p < 4; ++p) {               // V: 64 rows x 16 slots
            const int cv = p * 256 + tid;
            const int vr = cv >> 4, vsl = cv & 15;
            async_copy16(&vtg[base + (size_t)vr * 2048 + kb + ((vsl ^ (vr & 15)) * 8)],
                         &vT[buf][cv * 8]);
        }
    };

    bf16x8 qf[2][2];
#pragma unroll
    for (int qn = 0; qn < 2; ++qn)
#pragma unroll
        for (int kh = 0; kh < 2; ++kh)
            qf[qn][kh] = *(const bf16x8*)&qg[base + (size_t)(qbase + qn * 16 + l16) * DHEAD +
                                            kh * 32 + quad * 8];

    float li[2] = {0.f, 0.f};
    f32x4 accO[2][4];
#pragma unroll
    for (int qn = 0; qn < 2; ++qn)
#pragma unroll
        for (int nc = 0; nc < 4; ++nc) accO[qn][nc] = (f32x4){0.f, 0.f, 0.f, 0.f};

    auto tile_step = [&](int buf, int s) {
        const int kb = s * 128;
        bf16x8 pf[2][4];                        // P fragments, 4 x 32-key chunks
#pragma unroll
        for (int h = 0; h < 2; ++h) {           // two 64-key halves (reg liveness)
            f32x4 sf[2][4];
#pragma unroll
            for (int m = 0; m < 4; ++m) {
                const int row = h * 64 + m * 16 + l16;
                const int rb = row * 64;
                const int sw = (row & 7) * 8;
                const bf16x8 kf0 = *(const bf16x8*)&kT[buf][rb + ((quad * 8) ^ sw)];
                const bf16x8 kf1 = *(const bf16x8*)&kT[buf][rb + ((32 + quad * 8) ^ sw)];
#pragma unroll
                for (int qn = 0; qn < 2; ++qn) {
                    f32x4 z = (f32x4){0.f, 0.f, 0.f, 0.f};
                    z = __builtin_amdgcn_mfma_f32_16x16x32_bf16(kf0, qf[qn][0], z, 0, 0, 0);
                    sf[qn][m] = __builtin_amdgcn_mfma_f32_16x16x32_bf16(kf1, qf[qn][1], z,
                                                                        0, 0, 0);
                }
            }
            if (kb + h * 64 + 64 > qbase) {
#pragma unroll
                for (int qn = 0; qn < 2; ++qn) {
                    const int myq = qbase + qn * 16 + l16;
#pragma unroll
                    for (int m = 0; m < 4; ++m)
#pragma unroll
                        for (int r = 0; r < 4; ++r)
                            if (kb + h * 64 + m * 16 + quad * 4 + r > myq)
                                sf[qn][m][r] = -3.0e38f;
                }
            }
            // softmax exp2 + rowsum; pack bf16 pairs in-register
            unsigned c0[2][4], c1[2][4];
#pragma unroll
            for (int qn = 0; qn < 2; ++qn) {
                float rs = 0.f;
#pragma unroll
                for (int m = 0; m < 4; ++m) {
                    const float p0 = exp2_fast(sf[qn][m][0]);
                    const float p1 = exp2_fast(sf[qn][m][1]);
                    const float p2 = exp2_fast(sf[qn][m][2]);
                    const float p3 = exp2_fast(sf[qn][m][3]);
                    rs += (p0 + p1) + (p2 + p3);
                    asm("v_cvt_pk_bf16_f32 %0, %1, %2" : "=v"(c0[qn][m]) : "v"(p0), "v"(p1));
                    asm("v_cvt_pk_bf16_f32 %0, %1, %2" : "=v"(c1[qn][m]) : "v"(p2), "v"(p3));
                }
                li[qn] += rs;
            }
            // in-register transpose to PV B-fragments (permlane32 + permlane16)
#pragma unroll
            for (int qn = 0; qn < 2; ++qn)
#pragma unroll
                for (int ks = 0; ks < 2; ++ks) {
                    unsigned a0 = c0[qn][2 * ks], b0 = c0[qn][2 * ks + 1];
                    unsigned a1 = c1[qn][2 * ks], b1 = c1[qn][2 * ks + 1];
                    asm("v_permlane32_swap_b32 %0, %1" : "+v"(a0), "+v"(b0));
                    asm("v_permlane16_swap_b32 %0, %1" : "+v"(a0), "+v"(b0));
                    asm("v_permlane32_swap_b32 %0, %1" : "+v"(a1), "+v"(b1));
                    asm("v_permlane16_swap_b32 %0, %1" : "+v"(a1), "+v"(b1));
                    union { bf16x8 v; unsigned u[4]; } t8;
                    t8.u[0] = a0; t8.u[1] = a1; t8.u[2] = b0; t8.u[3] = b1;
                    pf[qn][h * 2 + ks] = t8.v;
                }
        }
        // PV: 4 key-chunks x 4 d-blocks x 2 qn = 32 MFMA
#pragma unroll
        for (int nc = 0; nc < 4; ++nc) {
            const int row = nc * 16 + l16;
            const int rb = row * 128;
#pragma unroll
            for (int ks = 0; ks < 4; ++ks) {
                const bf16x8 vf =
                    *(const bf16x8*)&vT[buf][rb + (((ks * 4 + quad) ^ (row & 15)) * 8)];
#pragma unroll
                for (int qn = 0; qn < 2; ++qn)
                    accO[qn][nc] = __builtin_amdgcn_mfma_f32_16x16x32_bf16(vf, pf[qn][ks],
                                                                          accO[qn][nc],
                                                                          0, 0, 0);
            }
        }
    };

    stage(0, 0);
    __syncthreads();
    int cur = 0;
    for (int s = 0; s < steps; ++s) {
        if (s + 1 < steps) stage(s + 1, cur ^ 1);
        tile_step(cur, s);
        __syncthreads();
        cur ^= 1;
    }

#pragma unroll
    for (int qn = 0; qn < 2; ++qn) {
        li[qn] += __shfl_xor(li[qn], 16, 64);
        li[qn] += __shfl_xor(li[qn], 32, 64);
        const float inv = 1.0f / li[qn];
        const int npos = qbase + qn * 16 + l16;
#pragma unroll
        for (int nc = 0; nc < 4; ++nc) {
            bf16x4 ow;
#pragma unroll
            for (int r = 0; r < 4; ++r) ow[r] = f2bf(accO[qn][nc][r] * inv);
            *(bf16x4*)&og[(size_t)(bb * 2048 + npos) * 1024 + hh * 64 + nc * 16 + quad * 4] = ow;
        }
    }
}

// ---------------------------------------------------------------------------
// Launch  (4 dispatches: prep, gemm_qkv, attn, gemm_out)
// ---------------------------------------------------------------------------
extern "C" void kernel_launch(void* const* d_in, const int* in_sizes, int n_in,
                              void* d_out, int out_size, void* d_ws, size_t ws_size,
                              hipStream_t stream) {
    const float* x     = (const float*)d_in[0];
    const float* gamma = (const float*)d_in[1];
    const float* w_qkv = (const float*)d_in[2];
    const float* w_out = (const float*)d_in[3];
    float* out = (float*)d_out;
    char* ws = (char*)d_ws;

    short* xn     = (short*)(ws);                    //  8 MB
    short* wqkvT  = (short*)(ws + 8388608);          //  6 MB
    short* woutT  = (short*)(ws + 14680064);         //  2 MB
    short* q      = (short*)(ws + 16777216);         //  8 MB: [32][2048][64]
    short* k      = q + 32 * 2048 * 64;              //  8 MB: [32][2048][64]
    short* vt     = k + 32 * 2048 * 64;              //  8 MB: [32][64][2048]
    short* attn   = (short*)(ws + 41943040);         //  8 MB

    // prep: 768 (wqkv T) + 256 (wout T) + 4096 (rmsnorm) = 5120 blocks
    prep_kernel<<<5120, 256, 0, stream>>>(x, gamma, w_qkv, w_out, xn, wqkvT, woutT);
    // 256x192 tile, BK=64, counted-vmcnt 2-deep pipeline: 256 blocks, 512 thr
    gemm_qkv<<<256, 512, 0, stream>>>(xn, wqkvT, q, vt);
    // 512 blocks: (bh, 128-query tile), pair-balanced; KVBLK=128 steps
    attn_kernel<<<512, 256, 0, stream>>>(q, k, vt, attn);
    // 128x64 tile, BK=64 swizzled, 2-phase: 16x32 = 512 blocks
    gemm_out<<<dim3(16, 32), 256, 0, stream>>>(attn, woutT, out);
}

// Round 8
// 163.436 us; speedup vs baseline: 1.0027x; 1.0027x over previous
//
#include <hip/hip_runtime.h>

// ---------------------------------------------------------------------------
// Types / helpers
// ---------------------------------------------------------------------------
typedef __attribute__((ext_vector_type(8))) short bf16x8;   // 8 bf16 = 4 VGPR
typedef __attribute__((ext_vector_type(4))) short bf16x4;   // 8 bytes
typedef __attribute__((ext_vector_type(4))) float f32x4;    // MFMA acc

static __device__ __forceinline__ short f2bf(float f) {      // RNE
    union { float f; unsigned u; } v; v.f = f;
    unsigned r = v.u + 0x7fffu + ((v.u >> 16) & 1u);
    return (short)(r >> 16);
}

// raw v_exp_f32: computes 2^x in one VALU op (libm exp2f = slow OCML path)
static __device__ __forceinline__ float exp2_fast(float x) {
    float r; asm("v_exp_f32 %0, %1" : "=v"(r) : "v"(x)); return r;
}

// async global->LDS, 16B per lane; lds dest MUST be base + lane*16 (m97/m104)
static __device__ __forceinline__ void async_copy16(const short* g, short* l) {
    __builtin_amdgcn_global_load_lds((const __attribute__((address_space(1))) void*)g,
                                     (__attribute__((address_space(3))) void*)l,
                                     16, 0, 0);
}

// raw barrier (no implicit vmcnt drain) + compile-time motion fences
#define BARX()                                            \
    do {                                                  \
        asm volatile("" ::: "memory");                    \
        __builtin_amdgcn_s_barrier();                     \
        __builtin_amdgcn_sched_barrier(0);                \
    } while (0)

#define HEADS 16
#define DHEAD 64
#define NSEQ  2048
#define DIM   1024
#define BATCH 2
#define ROWS  (BATCH * NSEQ)          // 4096
#define NQKV  (3 * HEADS * DHEAD)     // 3072

// q scale folded with log2(e): attn uses exp2 directly.  0.125 * log2(e)
#define QSCALE 0.18033688f

// ---------------------------------------------------------------------------
// Prep megakernel (unchanged) — one dispatch, roles by block range:
//   [0,768):      w_qkv [1024][3072] -> wqkvT [3072][1024]  (64x64 tiles)
//   [768,1024):   w_out [1024][1024] -> woutT [1024][1024]  (64x64 tiles)
//   [1024,5120):  rmsnorm row (blk-1024)
// ---------------------------------------------------------------------------
__global__ __launch_bounds__(256) void prep_kernel(const float* __restrict__ x,
                                                   const float* __restrict__ gamma,
                                                   const float* __restrict__ w_qkv,
                                                   const float* __restrict__ w_out,
                                                   short* __restrict__ xn,
                                                   short* __restrict__ wqkvT,
                                                   short* __restrict__ woutT) {
    const int blk = blockIdx.x;
    const int t = threadIdx.x;
    __shared__ float tile[64][65];
    __shared__ float part[4];

    if (blk < 1024) {
        // ---- transpose+cast role (64x64 tile) ----
        const float* in;  short* out;  int C, bx, by;
        if (blk < 768) { in = w_qkv; out = wqkvT; C = NQKV; bx = blk % 48; by = blk / 48; }
        else           { in = w_out; out = woutT; C = DIM;  bx = (blk - 768) & 15; by = (blk - 768) >> 4; }
        const int gx = bx * 64, gy = by * 64;
        const int lc4 = (t & 15) * 4;          // load col 0..60
        const int lr  = t >> 4;                // load row 0..15 (x4 passes)
#pragma unroll
        for (int p = 0; p < 4; ++p) {
            const float4 v = *(const float4*)&in[(size_t)(gy + p * 16 + lr) * C + gx + lc4];
            tile[p * 16 + lr][lc4 + 0] = v.x;
            tile[p * 16 + lr][lc4 + 1] = v.y;
            tile[p * 16 + lr][lc4 + 2] = v.z;
            tile[p * 16 + lr][lc4 + 3] = v.w;
        }
        __syncthreads();
        const int oc  = t >> 2;                // output row 0..63 (input col)
        const int or4 = (t & 3) * 16;          // 16 output elems per thread
#pragma unroll
        for (int j = 0; j < 4; ++j) {
            bf16x4 w;
#pragma unroll
            for (int r = 0; r < 4; ++r) w[r] = f2bf(tile[or4 + j * 4 + r][oc]);
            *(bf16x4*)&out[(size_t)(gx + oc) * DIM + gy + or4 + j * 4] = w;
        }
    } else {
        // ---- rmsnorm role ----
        const int row = blk - 1024;
        const float4 v = ((const float4*)(x + (size_t)row * DIM))[t];
        float s = v.x * v.x + v.y * v.y + v.z * v.z + v.w * v.w;
#pragma unroll
        for (int off = 32; off > 0; off >>= 1) s += __shfl_down(s, off, 64);
        if ((t & 63) == 0) part[t >> 6] = s;
        __syncthreads();
        const float tot = part[0] + part[1] + part[2] + part[3];
        const float scale = 32.0f / fmaxf(sqrtf(tot), 1e-12f);   // sqrt(1024)=32
        const float4 g = ((const float4*)gamma)[t];
        bf16x4 o;
        o[0] = f2bf(v.x * scale * g.x);
        o[1] = f2bf(v.y * scale * g.y);
        o[2] = f2bf(v.z * scale * g.z);
        o[3] = f2bf(v.w * scale * g.w);
        *(bf16x4*)(xn + (size_t)row * DIM + t * 4) = o;
    }
}

// ---------------------------------------------------------------------------
// QKV GEMM — REVERTED to round-6 4-phase structure (measured best, ~<=42us).
// Round-7 lesson: stage-issue must stay INTERLEAVED with quadrant-0 ds_reads
// (a dedicated stage region between barriers + clustered reads regressed +8us).
//   tile 256x192, BK=64, 8 waves; 4 phases/K-tile, all 7 next-tile stages
//   issued at phase 0, vmcnt(0) drain at phase 3 (~3 phases of margin).
//   XOR swizzle col ^ (row&7)*8 (linear gload_lds dest, pre-swz source).
// Epilogue: q/k scatter (q scaled QSCALE); V transposed to vt [b*h][d][n].
// ---------------------------------------------------------------------------
__global__ __launch_bounds__(512, 2) void gemm_qkv(const short* __restrict__ A,
                                                   const short* __restrict__ Bt,
                                                   short* __restrict__ qkOut,
                                                   short* __restrict__ vtOut) {
    __shared__ alignas(16) short lA[2][256 * 64];   // 64 KB
    __shared__ alignas(16) short lB[2][192 * 64];   // 48 KB
    const int tid = threadIdx.x;
    const int lane = tid & 63, wid = tid >> 6;
    const int quad = lane >> 4, l16 = lane & 15;
    const int wm = wid >> 2, wn = wid & 3;          // 2M x 4N waves

    int flat = blockIdx.x;
    flat = (flat & 7) * 32 + (flat >> 3);           // XCD chunk swizzle
    const int mb = (flat >> 4) * 256;
    const int nb = (flat & 15) * 192;

    f32x4 acc[8][3];
#pragma unroll
    for (int i = 0; i < 8; ++i)
#pragma unroll
        for (int j = 0; j < 3; ++j) acc[i][j] = (f32x4){0.f, 0.f, 0.f, 0.f};

    // staging: 512 thr x 16B = 64 rows x 128B per load; source col pre-swizzled
    const int srow = tid >> 3;                 // 0..63
    const int scol = (tid & 7) * 8;            // linear LDS col (shorts)
    const int scolx = scol ^ ((srow & 7) * 8); // swizzled global col

    auto stageA = [&](int kb, int buf) {
#pragma unroll
        for (int c = 0; c < 4; ++c) {
            const int row = c * 64 + srow;
            async_copy16(&A[(size_t)(mb + row) * 1024 + kb + scolx],
                         &lA[buf][row * 64 + scol]);
        }
    };
    auto stageB = [&](int kb, int buf) {
#pragma unroll
        for (int c = 0; c < 3; ++c) {
            const int row = c * 64 + srow;
            async_copy16(&Bt[(size_t)(nb + row) * 1024 + kb + scolx],
                         &lB[buf][row * 64 + scol]);
        }
    };
    // swizzled fragment reads (2-way banked = free)
    auto rdA = [&](int buf, int mt, int kh) -> bf16x8 {
        const int row = wm * 128 + mt * 16 + l16;
        const int col = (kh * 32 + quad * 8) ^ ((row & 7) * 8);
        return *(const bf16x8*)&lA[buf][row * 64 + col];
    };
    auto rdB = [&](int buf, int nt, int kh) -> bf16x8 {
        const int row = wn * 48 + nt * 16 + l16;
        const int col = (kh * 32 + quad * 8) ^ ((row & 7) * 8);
        return *(const bf16x8*)&lB[buf][row * 64 + col];
    };

    // prologue: tile 0 into buf 0, full drain, barrier
    stageA(0, 0);
    stageB(0, 0);
    asm volatile("s_waitcnt vmcnt(0)" ::: "memory");
    BARX();

    int cur = 0;
    for (int kt = 0; kt < 16; ++kt) {
        bf16x8 a[4][2], b01[2][2], b2[2];
        // ---- phase 0: quadrant (mt0-3 x nt0-1); issue ALL next-tile stages ----
#pragma unroll
        for (int mt = 0; mt < 4; ++mt)
#pragma unroll
            for (int kh = 0; kh < 2; ++kh) a[mt][kh] = rdA(cur, mt, kh);
#pragma unroll
        for (int nt = 0; nt < 2; ++nt)
#pragma unroll
            for (int kh = 0; kh < 2; ++kh) b01[nt][kh] = rdB(cur, nt, kh);
        if (kt < 15) {
            stageA((kt + 1) * 64, cur ^ 1);
            stageB((kt + 1) * 64, cur ^ 1);
        }
        BARX();
        __builtin_amdgcn_s_setprio(1);
#pragma unroll
        for (int kh = 0; kh < 2; ++kh)
#pragma unroll
            for (int mt = 0; mt < 4; ++mt)
#pragma unroll
                for (int nt = 0; nt < 2; ++nt)
                    acc[mt][nt] = __builtin_amdgcn_mfma_f32_16x16x32_bf16(
                        a[mt][kh], b01[nt][kh], acc[mt][nt], 0, 0, 0);
        __builtin_amdgcn_s_setprio(0);
        // ---- phase 1: quadrant (mt0-3 x nt2) ----
#pragma unroll
        for (int kh = 0; kh < 2; ++kh) b2[kh] = rdB(cur, 2, kh);
        BARX();
        __builtin_amdgcn_s_setprio(1);
#pragma unroll
        for (int kh = 0; kh < 2; ++kh)
#pragma unroll
            for (int mt = 0; mt < 4; ++mt)
                acc[mt][2] = __builtin_amdgcn_mfma_f32_16x16x32_bf16(
                    a[mt][kh], b2[kh], acc[mt][2], 0, 0, 0);
        __builtin_amdgcn_s_setprio(0);
        // ---- phase 2: quadrant (mt4-7 x nt2) ----
#pragma unroll
        for (int mt = 0; mt < 4; ++mt)
#pragma unroll
            for (int kh = 0; kh < 2; ++kh) a[mt][kh] = rdA(cur, mt + 4, kh);
        BARX();
        __builtin_amdgcn_s_setprio(1);
#pragma unroll
        for (int kh = 0; kh < 2; ++kh)
#pragma unroll
            for (int mt = 0; mt < 4; ++mt)
                acc[mt + 4][2] = __builtin_amdgcn_mfma_f32_16x16x32_bf16(
                    a[mt][kh], b2[kh], acc[mt + 4][2], 0, 0, 0);
        __builtin_amdgcn_s_setprio(0);
        // ---- phase 3: quadrant (mt4-7 x nt0-1); drain next-tile stages ----
        asm volatile("s_waitcnt vmcnt(0)" ::: "memory");   // loads >=3 phases old
        BARX();
        __builtin_amdgcn_s_setprio(1);
#pragma unroll
        for (int kh = 0; kh < 2; ++kh)
#pragma unroll
            for (int mt = 0; mt < 4; ++mt)
#pragma unroll
                for (int nt = 0; nt < 2; ++nt)
                    acc[mt + 4][nt] = __builtin_amdgcn_mfma_f32_16x16x32_bf16(
                        a[mt][kh], b01[nt][kh], acc[mt + 4][nt], 0, 0, 0);
        __builtin_amdgcn_s_setprio(0);
        cur ^= 1;
    }

    // ---- epilogue: q/k scatter + transposed V ----
#pragma unroll
    for (int mt = 0; mt < 8; ++mt) {
#pragma unroll
        for (int nt = 0; nt < 3; ++nt) {
            const int grow0 = mb + wm * 128 + mt * 16 + quad * 4;
            const int gcol  = nb + wn * 48 + nt * 16 + l16;
            const int s3 = gcol >> 10, rem = gcol & 1023;
            const int hh = rem >> 6, dd = rem & 63;
            const int bb = grow0 >> 11, npos0 = grow0 & 2047;
            if (s3 == 2) {
                bf16x4 vw;
#pragma unroll
                for (int r = 0; r < 4; ++r) vw[r] = f2bf(acc[mt][nt][r]);
                *(bf16x4*)&vtOut[((size_t)(bb * 16 + hh) * 64 + dd) * 2048 + npos0] = vw;
            } else {
                const float sc = (s3 == 0) ? QSCALE : 1.0f;
#pragma unroll
                for (int r = 0; r < 4; ++r)
                    qkOut[(size_t)((s3 * 32 + bb * 16 + hh) * 2048 + npos0 + r) * 64 + dd] =
                        f2bf(acc[mt][nt][r] * sc);
            }
        }
    }
}

// ---------------------------------------------------------------------------
// Output GEMM (unchanged): BK=64, XOR-swizzled, 2-phase.
// ---------------------------------------------------------------------------
__global__ __launch_bounds__(256, 3) void gemm_out(const short* __restrict__ A,
                                                   const short* __restrict__ Bt,
                                                   float* __restrict__ Cout) {
    __shared__ alignas(16) short lA2[2][128 * 64];   // 32 KB
    __shared__ alignas(16) short lB2[2][64 * 64];    // 16 KB
    const int tid = threadIdx.x;
    const int lane = tid & 63, wid = tid >> 6;
    const int quad = lane >> 4, l16 = lane & 15;

    const int nx = 16;                 // N blocks
    int flat = blockIdx.y * nx + blockIdx.x;
    flat = (flat & 7) * 64 + (flat >> 3);            // XCD swizzle (512/8=64)
    const int mb = (flat / nx) * 128, nb = (flat % nx) * 64;

    f32x4 acc[2][4];
#pragma unroll
    for (int i = 0; i < 2; ++i)
#pragma unroll
        for (int j = 0; j < 4; ++j) acc[i][j] = (f32x4){0.f, 0.f, 0.f, 0.f};

    auto stage = [&](int kb, int buf) {
#pragma unroll
        for (int p = 0; p < 4; ++p) {               // A: 128 rows x 8 slots
            const int ck = p * 256 + tid;
            const int ar = ck >> 3, as_ = ck & 7;
            async_copy16(&A[(size_t)(mb + ar) * 1024 + kb + ((as_ ^ (ar & 7)) * 8)],
                         &lA2[buf][ck * 8]);
        }
#pragma unroll
        for (int p = 0; p < 2; ++p) {               // B: 64 rows x 8 slots
            const int cb = p * 256 + tid;
            const int br = cb >> 3, bs = cb & 7;
            async_copy16(&Bt[(size_t)(nb + br) * 1024 + kb + ((bs ^ (br & 7)) * 8)],
                         &lB2[buf][cb * 8]);
        }
    };

    stage(0, 0);
    __syncthreads();

    int cur = 0;
    for (int kt = 0; kt < 16; ++kt) {
        if (kt + 1 < 16) stage((kt + 1) * 64, cur ^ 1);

        bf16x8 af[2][2], bfr[4][2];
#pragma unroll
        for (int mt = 0; mt < 2; ++mt) {
            const int row = wid * 32 + mt * 16 + l16;
#pragma unroll
            for (int kh = 0; kh < 2; ++kh)
                af[mt][kh] = *(const bf16x8*)&lA2[cur][row * 64 +
                                                      (((kh * 4 + quad) ^ (row & 7)) * 8)];
        }
#pragma unroll
        for (int nt = 0; nt < 4; ++nt) {
            const int row = nt * 16 + l16;
#pragma unroll
            for (int kh = 0; kh < 2; ++kh)
                bfr[nt][kh] = *(const bf16x8*)&lB2[cur][row * 64 +
                                                       (((kh * 4 + quad) ^ (row & 7)) * 8)];
        }
#pragma unroll
        for (int kh = 0; kh < 2; ++kh)
#pragma unroll
            for (int mt = 0; mt < 2; ++mt)
#pragma unroll
                for (int nt = 0; nt < 4; ++nt)
                    acc[mt][nt] = __builtin_amdgcn_mfma_f32_16x16x32_bf16(
                        af[mt][kh], bfr[nt][kh], acc[mt][nt], 0, 0, 0);
        __syncthreads();
        cur ^= 1;
    }

#pragma unroll
    for (int mt = 0; mt < 2; ++mt) {
#pragma unroll
        for (int nt = 0; nt < 4; ++nt) {
            const int grow0 = mb + wid * 32 + mt * 16 + quad * 4;
            const int gcol  = nb + nt * 16 + l16;
#pragma unroll
            for (int r = 0; r < 4; ++r)
                Cout[(size_t)(grow0 + r) * DIM + gcol] = acc[mt][nt][r];
        }
    }
}

// ---------------------------------------------------------------------------
// Causal flash attention v8: KVBLK=128; BOTH QK^T halves issued back-to-back
// before softmax (32-MFMA cluster; the two independent softmax chains then
// overlap).  sf[2][2][4] costs +32 VGPR — still <=256 at 2 waves/SIMD;
// occupancy stays LDS-limited at 2 blocks/CU.
// ---------------------------------------------------------------------------
__global__ __launch_bounds__(256, 2) void attn_kernel(const short* __restrict__ qg,
                                                      const short* __restrict__ kg,
                                                      const short* __restrict__ vtg,
                                                      short* __restrict__ og) {
    const int tid = threadIdx.x;
    const int wid = tid >> 6, lane = tid & 63;
    const int quad = lane >> 4, l16 = lane & 15;
    const int blk = blockIdx.x;                 // 0..511
    // balanced pairing: qt(c) + qt(c+256) = 15 for all c
    const int qt = (blk < 256) ? (15 - (blk >> 5)) : ((blk - 256) >> 5);
    const int bh = blk & 31;
    const size_t base = (size_t)bh * (NSEQ * DHEAD);
    const int bb = bh >> 4, hh = bh & 15;
    const int qbase = qt * 128 + wid * 32;      // this wave's first query
    const int steps = qt + 1;                   // 128-key steps

    __shared__ alignas(16) short kT[2][128 * 64];   // 16 KB each buf
    __shared__ alignas(16) short vT[2][64 * 128];   // 16 KB each buf

    auto stage = [&](int s, int buf) {
        const int kb = s * 128;
#pragma unroll
        for (int p = 0; p < 4; ++p) {               // K: 128 rows x 8 slots
            const int ck = p * 256 + tid;
            const int kr = ck >> 3, ksl = ck & 7;
            async_copy16(&kg[base + (size_t)(kb + kr) * 64 + ((ksl ^ (kr & 7)) * 8)],
                         &kT[buf][ck * 8]);
        }
#pragma unroll
        for (int p = 0; p < 4; ++p) {               // V: 64 rows x 16 slots
            const int cv = p * 256 + tid;
            const int vr = cv >> 4, vsl = cv & 15;
            async_copy16(&vtg[base + (size_t)vr * 2048 + kb + ((vsl ^ (vr & 15)) * 8)],
                         &vT[buf][cv * 8]);
        }
    };

    bf16x8 qf[2][2];
#pragma unroll
    for (int qn = 0; qn < 2; ++qn)
#pragma unroll
        for (int kh = 0; kh < 2; ++kh)
            qf[qn][kh] = *(const bf16x8*)&qg[base + (size_t)(qbase + qn * 16 + l16) * DHEAD +
                                            kh * 32 + quad * 8];

    float li[2] = {0.f, 0.f};
    f32x4 accO[2][4];
#pragma unroll
    for (int qn = 0; qn < 2; ++qn)
#pragma unroll
        for (int nc = 0; nc < 4; ++nc) accO[qn][nc] = (f32x4){0.f, 0.f, 0.f, 0.f};

    auto tile_step = [&](int buf, int s) {
        const int kb = s * 128;
        f32x4 sf[2][2][4];                      // [h][qn][m] — both halves live
        // ---- QK^T: all 32 MFMA issued back-to-back ----
#pragma unroll
        for (int h = 0; h < 2; ++h) {
#pragma unroll
            for (int m = 0; m < 4; ++m) {
                const int row = h * 64 + m * 16 + l16;
                const int rb = row * 64;
                const int sw = (row & 7) * 8;
                const bf16x8 kf0 = *(const bf16x8*)&kT[buf][rb + ((quad * 8) ^ sw)];
                const bf16x8 kf1 = *(const bf16x8*)&kT[buf][rb + ((32 + quad * 8) ^ sw)];
#pragma unroll
                for (int qn = 0; qn < 2; ++qn) {
                    f32x4 z = (f32x4){0.f, 0.f, 0.f, 0.f};
                    z = __builtin_amdgcn_mfma_f32_16x16x32_bf16(kf0, qf[qn][0], z, 0, 0, 0);
                    sf[h][qn][m] = __builtin_amdgcn_mfma_f32_16x16x32_bf16(kf1, qf[qn][1], z,
                                                                           0, 0, 0);
                }
            }
        }
        // ---- causal mask (wave-uniform branch; only the last step fires) ----
#pragma unroll
        for (int h = 0; h < 2; ++h) {
            if (kb + h * 64 + 64 > qbase) {
#pragma unroll
                for (int qn = 0; qn < 2; ++qn) {
                    const int myq = qbase + qn * 16 + l16;
#pragma unroll
                    for (int m = 0; m < 4; ++m)
#pragma unroll
                        for (int r = 0; r < 4; ++r)
                            if (kb + h * 64 + m * 16 + quad * 4 + r > myq)
                                sf[h][qn][m][r] = -3.0e38f;
                }
            }
        }
        // ---- softmax both halves (independent chains overlap) ----
        bf16x8 pf[2][4];                        // [qn][key-chunk]
#pragma unroll
        for (int h = 0; h < 2; ++h) {
            unsigned c0[2][4], c1[2][4];
#pragma unroll
            for (int qn = 0; qn < 2; ++qn) {
                float rs = 0.f;
#pragma unroll
                for (int m = 0; m < 4; ++m) {
                    const float p0 = exp2_fast(sf[h][qn][m][0]);
                    const float p1 = exp2_fast(sf[h][qn][m][1]);
                    const float p2 = exp2_fast(sf[h][qn][m][2]);
                    const float p3 = exp2_fast(sf[h][qn][m][3]);
                    rs += (p0 + p1) + (p2 + p3);
                    asm("v_cvt_pk_bf16_f32 %0, %1, %2" : "=v"(c0[qn][m]) : "v"(p0), "v"(p1));
                    asm("v_cvt_pk_bf16_f32 %0, %1, %2" : "=v"(c1[qn][m]) : "v"(p2), "v"(p3));
                }
                li[qn] += rs;
            }
            // in-register transpose to PV B-fragments (permlane32 + permlane16)
#pragma unroll
            for (int qn = 0; qn < 2; ++qn)
#pragma unroll
                for (int ks = 0; ks < 2; ++ks) {
                    unsigned a0 = c0[qn][2 * ks], b0 = c0[qn][2 * ks + 1];
                    unsigned a1 = c1[qn][2 * ks], b1 = c1[qn][2 * ks + 1];
                    asm("v_permlane32_swap_b32 %0, %1" : "+v"(a0), "+v"(b0));
                    asm("v_permlane16_swap_b32 %0, %1" : "+v"(a0), "+v"(b0));
                    asm("v_permlane32_swap_b32 %0, %1" : "+v"(a1), "+v"(b1));
                    asm("v_permlane16_swap_b32 %0, %1" : "+v"(a1), "+v"(b1));
                    union { bf16x8 v; unsigned u[4]; } t8;
                    t8.u[0] = a0; t8.u[1] = a1; t8.u[2] = b0; t8.u[3] = b1;
                    pf[qn][h * 2 + ks] = t8.v;
                }
        }
        // ---- PV: 4 key-chunks x 4 d-blocks x 2 qn = 32 MFMA ----
#pragma unroll
        for (int nc = 0; nc < 4; ++nc) {
            const int row = nc * 16 + l16;
            const int rb = row * 128;
#pragma unroll
            for (int ks = 0; ks < 4; ++ks) {
                const bf16x8 vf =
                    *(const bf16x8*)&vT[buf][rb + (((ks * 4 + quad) ^ (row & 15)) * 8)];
#pragma unroll
                for (int qn = 0; qn < 2; ++qn)
                    accO[qn][nc] = __builtin_amdgcn_mfma_f32_16x16x32_bf16(vf, pf[qn][ks],
                                                                          accO[qn][nc],
                                                                          0, 0, 0);
            }
        }
    };

    stage(0, 0);
    __syncthreads();
    int cur = 0;
    for (int s = 0; s < steps; ++s) {
        if (s + 1 < steps) stage(s + 1, cur ^ 1);
        tile_step(cur, s);
        __syncthreads();
        cur ^= 1;
    }

#pragma unroll
    for (int qn = 0; qn < 2; ++qn) {
        li[qn] += __shfl_xor(li[qn], 16, 64);
        li[qn] += __shfl_xor(li[qn], 32, 64);
        const float inv = 1.0f / li[qn];
        const int npos = qbase + qn * 16 + l16;
#pragma unroll
        for (int nc = 0; nc < 4; ++nc) {
            bf16x4 ow;
#pragma unroll
            for (int r = 0; r < 4; ++r) ow[r] = f2bf(accO[qn][nc][r] * inv);
            *(bf16x4*)&og[(size_t)(bb * 2048 + npos) * 1024 + hh * 64 + nc * 16 + quad * 4] = ow;
        }
    }
}

// ---------------------------------------------------------------------------
// Launch  (4 dispatches: prep, gemm_qkv, attn, gemm_out)
// ---------------------------------------------------------------------------
extern "C" void kernel_launch(void* const* d_in, const int* in_sizes, int n_in,
                              void* d_out, int out_size, void* d_ws, size_t ws_size,
                              hipStream_t stream) {
    const float* x     = (const float*)d_in[0];
    const float* gamma = (const float*)d_in[1];
    const float* w_qkv = (const float*)d_in[2];
    const float* w_out = (const float*)d_in[3];
    float* out = (float*)d_out;
    char* ws = (char*)d_ws;

    short* xn     = (short*)(ws);                    //  8 MB
    short* wqkvT  = (short*)(ws + 8388608);          //  6 MB
    short* woutT  = (short*)(ws + 14680064);         //  2 MB
    short* q      = (short*)(ws + 16777216);         //  8 MB: [32][2048][64]
    short* k      = q + 32 * 2048 * 64;              //  8 MB: [32][2048][64]
    short* vt     = k + 32 * 2048 * 64;              //  8 MB: [32][64][2048]
    short* attn   = (short*)(ws + 41943040);         //  8 MB

    // prep: 768 (wqkv T) + 256 (wout T) + 4096 (rmsnorm) = 5120 blocks
    prep_kernel<<<5120, 256, 0, stream>>>(x, gamma, w_qkv, w_out, xn, wqkvT, woutT);
    // 256x192 tile, BK=64, 4-phase: 256 blocks = 1/CU, 512 threads
    gemm_qkv<<<256, 512, 0, stream>>>(xn, wqkvT, q, vt);
    // 512 blocks: (bh, 128-query tile), pair-balanced; KVBLK=128 steps
    attn_kernel<<<512, 256, 0, stream>>>(q, k, vt, attn);
    // 128x64 tile, BK=64 swizzled, 2-phase: 16x32 = 512 blocks
    gemm_out<<<dim3(16, 32), 256, 0, stream>>>(attn, woutT, out);
}

// Round 9
// 160.809 us; speedup vs baseline: 1.0191x; 1.0163x over previous
//
#include <hip/hip_runtime.h>

// ---------------------------------------------------------------------------
// Types / helpers
// ---------------------------------------------------------------------------
typedef __attribute__((ext_vector_type(8))) short bf16x8;   // 8 bf16 = 4 VGPR
typedef __attribute__((ext_vector_type(4))) short bf16x4;   // 8 bytes
typedef __attribute__((ext_vector_type(4))) float f32x4;    // MFMA acc

static __device__ __forceinline__ short f2bf(float f) {      // RNE
    union { float f; unsigned u; } v; v.f = f;
    unsigned r = v.u + 0x7fffu + ((v.u >> 16) & 1u);
    return (short)(r >> 16);
}

// raw v_exp_f32: computes 2^x in one VALU op (libm exp2f = slow OCML path)
static __device__ __forceinline__ float exp2_fast(float x) {
    float r; asm("v_exp_f32 %0, %1" : "=v"(r) : "v"(x)); return r;
}

// async global->LDS, 16B per lane; lds dest MUST be base + lane*16 (m97/m104)
static __device__ __forceinline__ void async_copy16(const short* g, short* l) {
    __builtin_amdgcn_global_load_lds((const __attribute__((address_space(1))) void*)g,
                                     (__attribute__((address_space(3))) void*)l,
                                     16, 0, 0);
}

// raw barrier (no implicit vmcnt drain) + compile-time motion fences
#define BARX()                                            \
    do {                                                  \
        asm volatile("" ::: "memory");                    \
        __builtin_amdgcn_s_barrier();                     \
        __builtin_amdgcn_sched_barrier(0);                \
    } while (0)

#define HEADS 16
#define DHEAD 64
#define NSEQ  2048
#define DIM   1024
#define BATCH 2
#define ROWS  (BATCH * NSEQ)          // 4096
#define NQKV  (3 * HEADS * DHEAD)     // 3072

// q scale folded with log2(e): attn uses exp2 directly.  0.125 * log2(e)
#define QSCALE 0.18033688f

// ---------------------------------------------------------------------------
// Prep megakernel (unchanged) — one dispatch, roles by block range:
//   [0,768):      w_qkv [1024][3072] -> wqkvT [3072][1024]  (64x64 tiles)
//   [768,1024):   w_out [1024][1024] -> woutT [1024][1024]  (64x64 tiles)
//   [1024,5120):  rmsnorm row (blk-1024)
// ---------------------------------------------------------------------------
__global__ __launch_bounds__(256) void prep_kernel(const float* __restrict__ x,
                                                   const float* __restrict__ gamma,
                                                   const float* __restrict__ w_qkv,
                                                   const float* __restrict__ w_out,
                                                   short* __restrict__ xn,
                                                   short* __restrict__ wqkvT,
                                                   short* __restrict__ woutT) {
    const int blk = blockIdx.x;
    const int t = threadIdx.x;
    __shared__ float tile[64][65];
    __shared__ float part[4];

    if (blk < 1024) {
        // ---- transpose+cast role (64x64 tile) ----
        const float* in;  short* out;  int C, bx, by;
        if (blk < 768) { in = w_qkv; out = wqkvT; C = NQKV; bx = blk % 48; by = blk / 48; }
        else           { in = w_out; out = woutT; C = DIM;  bx = (blk - 768) & 15; by = (blk - 768) >> 4; }
        const int gx = bx * 64, gy = by * 64;
        const int lc4 = (t & 15) * 4;          // load col 0..60
        const int lr  = t >> 4;                // load row 0..15 (x4 passes)
#pragma unroll
        for (int p = 0; p < 4; ++p) {
            const float4 v = *(const float4*)&in[(size_t)(gy + p * 16 + lr) * C + gx + lc4];
            tile[p * 16 + lr][lc4 + 0] = v.x;
            tile[p * 16 + lr][lc4 + 1] = v.y;
            tile[p * 16 + lr][lc4 + 2] = v.z;
            tile[p * 16 + lr][lc4 + 3] = v.w;
        }
        __syncthreads();
        const int oc  = t >> 2;                // output row 0..63 (input col)
        const int or4 = (t & 3) * 16;          // 16 output elems per thread
#pragma unroll
        for (int j = 0; j < 4; ++j) {
            bf16x4 w;
#pragma unroll
            for (int r = 0; r < 4; ++r) w[r] = f2bf(tile[or4 + j * 4 + r][oc]);
            *(bf16x4*)&out[(size_t)(gx + oc) * DIM + gy + or4 + j * 4] = w;
        }
    } else {
        // ---- rmsnorm role ----
        const int row = blk - 1024;
        const float4 v = ((const float4*)(x + (size_t)row * DIM))[t];
        float s = v.x * v.x + v.y * v.y + v.z * v.z + v.w * v.w;
#pragma unroll
        for (int off = 32; off > 0; off >>= 1) s += __shfl_down(s, off, 64);
        if ((t & 63) == 0) part[t >> 6] = s;
        __syncthreads();
        const float tot = part[0] + part[1] + part[2] + part[3];
        const float scale = 32.0f / fmaxf(sqrtf(tot), 1e-12f);   // sqrt(1024)=32
        const float4 g = ((const float4*)gamma)[t];
        bf16x4 o;
        o[0] = f2bf(v.x * scale * g.x);
        o[1] = f2bf(v.y * scale * g.y);
        o[2] = f2bf(v.z * scale * g.z);
        o[3] = f2bf(v.w * scale * g.w);
        *(bf16x4*)(xn + (size_t)row * DIM + t * 4) = o;
    }
}

// ---------------------------------------------------------------------------
// QKV GEMM v5: 128x192 tile @ 2 blocks/CU (m114 cross-block overlap).
//   The 256x192/112KB config was 1 block/CU = one barrier domain: every
//   barrier stalled the whole CU (per-tile ~6000cy vs ~1200cy of real work).
//   Now: 4 waves/block (2Mx2N), 80 KB LDS -> 2 blocks/CU = two independent
//   barrier domains interleaving each other's drain bubbles.
//   2 phases/tile, 2 barriers/tile; stage issued WITH phase-0 ds_reads
//   (round-7 lesson: never serialize the stage region); vmcnt(0) at tile
//   end waits on stages issued ~2 MFMA-clusters earlier.
//   XOR swizzle col ^ (row&7)*8 (linear gload_lds dest, pre-swz source).
//   Grid 32x16 = 512 (%8==0 -> bijective XCD chunk swizzle).
// Epilogue: q/k scatter (q scaled QSCALE); V transposed to vt [b*h][d][n].
// ---------------------------------------------------------------------------
__global__ __launch_bounds__(256, 2) void gemm_qkv(const short* __restrict__ A,
                                                   const short* __restrict__ Bt,
                                                   short* __restrict__ qkOut,
                                                   short* __restrict__ vtOut) {
    __shared__ alignas(16) short lA[2][128 * 64];   // 32 KB
    __shared__ alignas(16) short lB[2][192 * 64];   // 48 KB
    const int tid = threadIdx.x;
    const int lane = tid & 63, wid = tid >> 6;      // 4 waves
    const int quad = lane >> 4, l16 = lane & 15;
    const int wm = wid >> 1, wn = wid & 1;          // 2M x 2N waves

    int flat = blockIdx.x;
    flat = (flat & 7) * 64 + (flat >> 3);           // XCD chunk swizzle (512/8)
    const int mb = (flat >> 4) * 128;
    const int nb = (flat & 15) * 192;

    f32x4 acc[4][6];                                // per-wave 64x96
#pragma unroll
    for (int i = 0; i < 4; ++i)
#pragma unroll
        for (int j = 0; j < 6; ++j) acc[i][j] = (f32x4){0.f, 0.f, 0.f, 0.f};

    // staging: 256 thr x 16B = 32 rows x 128B per load; source col pre-swizzled
    const int srow = tid >> 3;                 // 0..31
    const int scol = (tid & 7) * 8;            // linear LDS col (shorts)
    const int scolx = scol ^ ((srow & 7) * 8); // swizzled global col

    auto stageA = [&](int kb, int buf) {
#pragma unroll
        for (int c = 0; c < 4; ++c) {
            const int row = c * 32 + srow;
            async_copy16(&A[(size_t)(mb + row) * 1024 + kb + scolx],
                         &lA[buf][row * 64 + scol]);
        }
    };
    auto stageB = [&](int kb, int buf) {
#pragma unroll
        for (int c = 0; c < 6; ++c) {
            const int row = c * 32 + srow;
            async_copy16(&Bt[(size_t)(nb + row) * 1024 + kb + scolx],
                         &lB[buf][row * 64 + scol]);
        }
    };
    // swizzled fragment reads (2-way banked = free)
    auto rdA = [&](int buf, int mt, int kh) -> bf16x8 {
        const int row = wm * 64 + mt * 16 + l16;
        const int col = (kh * 32 + quad * 8) ^ ((row & 7) * 8);
        return *(const bf16x8*)&lA[buf][row * 64 + col];
    };
    auto rdB = [&](int buf, int nt, int kh) -> bf16x8 {
        const int row = wn * 96 + nt * 16 + l16;
        const int col = (kh * 32 + quad * 8) ^ ((row & 7) * 8);
        return *(const bf16x8*)&lB[buf][row * 64 + col];
    };

    // prologue: tile 0 into buf 0, full drain, barrier
    stageA(0, 0);
    stageB(0, 0);
    asm volatile("s_waitcnt vmcnt(0)" ::: "memory");
    BARX();

    int cur = 0;
    for (int kt = 0; kt < 16; ++kt) {
        bf16x8 a[4][2], b[3][2];
        // ---- phase 0: read A(all mt) + B(nt0-2); issue next-tile stages ----
#pragma unroll
        for (int mt = 0; mt < 4; ++mt)
#pragma unroll
            for (int kh = 0; kh < 2; ++kh) a[mt][kh] = rdA(cur, mt, kh);
#pragma unroll
        for (int nt = 0; nt < 3; ++nt)
#pragma unroll
            for (int kh = 0; kh < 2; ++kh) b[nt][kh] = rdB(cur, nt, kh);
        if (kt < 15) {
            stageA((kt + 1) * 64, cur ^ 1);
            stageB((kt + 1) * 64, cur ^ 1);
        }
        BARX();
        __builtin_amdgcn_s_setprio(1);
#pragma unroll
        for (int kh = 0; kh < 2; ++kh)
#pragma unroll
            for (int mt = 0; mt < 4; ++mt)
#pragma unroll
                for (int nt = 0; nt < 3; ++nt)
                    acc[mt][nt] = __builtin_amdgcn_mfma_f32_16x16x32_bf16(
                        a[mt][kh], b[nt][kh], acc[mt][nt], 0, 0, 0);
        __builtin_amdgcn_s_setprio(0);
        // ---- phase 1: read B(nt3-5); MFMA; drain stages at tile end ----
#pragma unroll
        for (int nt = 0; nt < 3; ++nt)
#pragma unroll
            for (int kh = 0; kh < 2; ++kh) b[nt][kh] = rdB(cur, nt + 3, kh);
        BARX();
        __builtin_amdgcn_s_setprio(1);
#pragma unroll
        for (int kh = 0; kh < 2; ++kh)
#pragma unroll
            for (int mt = 0; mt < 4; ++mt)
#pragma unroll
                for (int nt = 0; nt < 3; ++nt)
                    acc[mt][nt + 3] = __builtin_amdgcn_mfma_f32_16x16x32_bf16(
                        a[mt][kh], b[nt][kh], acc[mt][nt + 3], 0, 0, 0);
        __builtin_amdgcn_s_setprio(0);
        // stages (issued at phase 0, ~2 MFMA clusters ago) must land before
        // next tile's phase-0 reads; WAR separation for buf swap
        asm volatile("s_waitcnt vmcnt(0)" ::: "memory");
        BARX();
        cur ^= 1;
    }

    // ---- epilogue: q/k scatter + transposed V ----
#pragma unroll
    for (int mt = 0; mt < 4; ++mt) {
#pragma unroll
        for (int nt = 0; nt < 6; ++nt) {
            const int grow0 = mb + wm * 64 + mt * 16 + quad * 4;
            const int gcol  = nb + wn * 96 + nt * 16 + l16;
            const int s3 = gcol >> 10, rem = gcol & 1023;   // uniform per 16-col
            const int hh = rem >> 6, dd = rem & 63;
            const int bb = grow0 >> 11, npos0 = grow0 & 2047;
            if (s3 == 2) {
                bf16x4 vw;
#pragma unroll
                for (int r = 0; r < 4; ++r) vw[r] = f2bf(acc[mt][nt][r]);
                *(bf16x4*)&vtOut[((size_t)(bb * 16 + hh) * 64 + dd) * 2048 + npos0] = vw;
            } else {
                const float sc = (s3 == 0) ? QSCALE : 1.0f;
#pragma unroll
                for (int r = 0; r < 4; ++r)
                    qkOut[(size_t)((s3 * 32 + bb * 16 + hh) * 2048 + npos0 + r) * 64 + dd] =
                        f2bf(acc[mt][nt][r] * sc);
            }
        }
    }
}

// ---------------------------------------------------------------------------
// Output GEMM (unchanged): BK=64, XOR-swizzled, 2-phase.
// ---------------------------------------------------------------------------
__global__ __launch_bounds__(256, 3) void gemm_out(const short* __restrict__ A,
                                                   const short* __restrict__ Bt,
                                                   float* __restrict__ Cout) {
    __shared__ alignas(16) short lA2[2][128 * 64];   // 32 KB
    __shared__ alignas(16) short lB2[2][64 * 64];    // 16 KB
    const int tid = threadIdx.x;
    const int lane = tid & 63, wid = tid >> 6;
    const int quad = lane >> 4, l16 = lane & 15;

    const int nx = 16;                 // N blocks
    int flat = blockIdx.y * nx + blockIdx.x;
    flat = (flat & 7) * 64 + (flat >> 3);            // XCD swizzle (512/8=64)
    const int mb = (flat / nx) * 128, nb = (flat % nx) * 64;

    f32x4 acc[2][4];
#pragma unroll
    for (int i = 0; i < 2; ++i)
#pragma unroll
        for (int j = 0; j < 4; ++j) acc[i][j] = (f32x4){0.f, 0.f, 0.f, 0.f};

    auto stage = [&](int kb, int buf) {
#pragma unroll
        for (int p = 0; p < 4; ++p) {               // A: 128 rows x 8 slots
            const int ck = p * 256 + tid;
            const int ar = ck >> 3, as_ = ck & 7;
            async_copy16(&A[(size_t)(mb + ar) * 1024 + kb + ((as_ ^ (ar & 7)) * 8)],
                         &lA2[buf][ck * 8]);
        }
#pragma unroll
        for (int p = 0; p < 2; ++p) {               // B: 64 rows x 8 slots
            const int cb = p * 256 + tid;
            const int br = cb >> 3, bs = cb & 7;
            async_copy16(&Bt[(size_t)(nb + br) * 1024 + kb + ((bs ^ (br & 7)) * 8)],
                         &lB2[buf][cb * 8]);
        }
    };

    stage(0, 0);
    __syncthreads();

    int cur = 0;
    for (int kt = 0; kt < 16; ++kt) {
        if (kt + 1 < 16) stage((kt + 1) * 64, cur ^ 1);

        bf16x8 af[2][2], bfr[4][2];
#pragma unroll
        for (int mt = 0; mt < 2; ++mt) {
            const int row = wid * 32 + mt * 16 + l16;
#pragma unroll
            for (int kh = 0; kh < 2; ++kh)
                af[mt][kh] = *(const bf16x8*)&lA2[cur][row * 64 +
                                                      (((kh * 4 + quad) ^ (row & 7)) * 8)];
        }
#pragma unroll
        for (int nt = 0; nt < 4; ++nt) {
            const int row = nt * 16 + l16;
#pragma unroll
            for (int kh = 0; kh < 2; ++kh)
                bfr[nt][kh] = *(const bf16x8*)&lB2[cur][row * 64 +
                                                       (((kh * 4 + quad) ^ (row & 7)) * 8)];
        }
#pragma unroll
        for (int kh = 0; kh < 2; ++kh)
#pragma unroll
            for (int mt = 0; mt < 2; ++mt)
#pragma unroll
                for (int nt = 0; nt < 4; ++nt)
                    acc[mt][nt] = __builtin_amdgcn_mfma_f32_16x16x32_bf16(
                        af[mt][kh], bfr[nt][kh], acc[mt][nt], 0, 0, 0);
        __syncthreads();
        cur ^= 1;
    }

#pragma unroll
    for (int mt = 0; mt < 2; ++mt) {
#pragma unroll
        for (int nt = 0; nt < 4; ++nt) {
            const int grow0 = mb + wid * 32 + mt * 16 + quad * 4;
            const int gcol  = nb + nt * 16 + l16;
#pragma unroll
            for (int r = 0; r < 4; ++r)
                Cout[(size_t)(grow0 + r) * DIM + gcol] = acc[mt][nt][r];
        }
    }
}

// ---------------------------------------------------------------------------
// Causal flash attention v8 (unchanged from round 8): KVBLK=128, batched
// QK^T, in-register P transpose, raw v_exp, pair-balanced qt map.
// ---------------------------------------------------------------------------
__global__ __launch_bounds__(256, 2) void attn_kernel(const short* __restrict__ qg,
                                                      const short* __restrict__ kg,
                                                      const short* __restrict__ vtg,
                                                      short* __restrict__ og) {
    const int tid = threadIdx.x;
    const int wid = tid >> 6, lane = tid & 63;
    const int quad = lane >> 4, l16 = lane & 15;
    const int blk = blockIdx.x;                 // 0..511
    // balanced pairing: qt(c) + qt(c+256) = 15 for all c
    const int qt = (blk < 256) ? (15 - (blk >> 5)) : ((blk - 256) >> 5);
    const int bh = blk & 31;
    const size_t base = (size_t)bh * (NSEQ * DHEAD);
    const int bb = bh >> 4, hh = bh & 15;
    const int qbase = qt * 128 + wid * 32;      // this wave's first query
    const int steps = qt + 1;                   // 128-key steps

    __shared__ alignas(16) short kT[2][128 * 64];   // 16 KB each buf
    __shared__ alignas(16) short vT[2][64 * 128];   // 16 KB each buf

    auto stage = [&](int s, int buf) {
        const int kb = s * 128;
#pragma unroll
        for (int p = 0; p < 4; ++p) {               // K: 128 rows x 8 slots
            const int ck = p * 256 + tid;
            const int kr = ck >> 3, ksl = ck & 7;
            async_copy16(&kg[base + (size_t)(kb + kr) * 64 + ((ksl ^ (kr & 7)) * 8)],
                         &kT[buf][ck * 8]);
        }
#pragma unroll
        for (int p = 0; p < 4; ++p) {               // V: 64 rows x 16 slots
            const int cv = p * 256 + tid;
            const int vr = cv >> 4, vsl = cv & 15;
            async_copy16(&vtg[base + (size_t)vr * 2048 + kb + ((vsl ^ (vr & 15)) * 8)],
                         &vT[buf][cv * 8]);
        }
    };

    bf16x8 qf[2][2];
#pragma unroll
    for (int qn = 0; qn < 2; ++qn)
#pragma unroll
        for (int kh = 0; kh < 2; ++kh)
            qf[qn][kh] = *(const bf16x8*)&qg[base + (size_t)(qbase + qn * 16 + l16) * DHEAD +
                                            kh * 32 + quad * 8];

    float li[2] = {0.f, 0.f};
    f32x4 accO[2][4];
#pragma unroll
    for (int qn = 0; qn < 2; ++qn)
#pragma unroll
        for (int nc = 0; nc < 4; ++nc) accO[qn][nc] = (f32x4){0.f, 0.f, 0.f, 0.f};

    auto tile_step = [&](int buf, int s) {
        const int kb = s * 128;
        f32x4 sf[2][2][4];                      // [h][qn][m] — both halves live
        // ---- QK^T: all 32 MFMA issued back-to-back ----
#pragma unroll
        for (int h = 0; h < 2; ++h) {
#pragma unroll
            for (int m = 0; m < 4; ++m) {
                const int row = h * 64 + m * 16 + l16;
                const int rb = row * 64;
                const int sw = (row & 7) * 8;
                const bf16x8 kf0 = *(const bf16x8*)&kT[buf][rb + ((quad * 8) ^ sw)];
                const bf16x8 kf1 = *(const bf16x8*)&kT[buf][rb + ((32 + quad * 8) ^ sw)];
#pragma unroll
                for (int qn = 0; qn < 2; ++qn) {
                    f32x4 z = (f32x4){0.f, 0.f, 0.f, 0.f};
                    z = __builtin_amdgcn_mfma_f32_16x16x32_bf16(kf0, qf[qn][0], z, 0, 0, 0);
                    sf[h][qn][m] = __builtin_amdgcn_mfma_f32_16x16x32_bf16(kf1, qf[qn][1], z,
                                                                           0, 0, 0);
                }
            }
        }
        // ---- causal mask (wave-uniform branch; only the last step fires) ----
#pragma unroll
        for (int h = 0; h < 2; ++h) {
            if (kb + h * 64 + 64 > qbase) {
#pragma unroll
                for (int qn = 0; qn < 2; ++qn) {
                    const int myq = qbase + qn * 16 + l16;
#pragma unroll
                    for (int m = 0; m < 4; ++m)
#pragma unroll
                        for (int r = 0; r < 4; ++r)
                            if (kb + h * 64 + m * 16 + quad * 4 + r > myq)
                                sf[h][qn][m][r] = -3.0e38f;
                }
            }
        }
        // ---- softmax both halves (independent chains overlap) ----
        bf16x8 pf[2][4];                        // [qn][key-chunk]
#pragma unroll
        for (int h = 0; h < 2; ++h) {
            unsigned c0[2][4], c1[2][4];
#pragma unroll
            for (int qn = 0; qn < 2; ++qn) {
                float rs = 0.f;
#pragma unroll
                for (int m = 0; m < 4; ++m) {
                    const float p0 = exp2_fast(sf[h][qn][m][0]);
                    const float p1 = exp2_fast(sf[h][qn][m][1]);
                    const float p2 = exp2_fast(sf[h][qn][m][2]);
                    const float p3 = exp2_fast(sf[h][qn][m][3]);
                    rs += (p0 + p1) + (p2 + p3);
                    asm("v_cvt_pk_bf16_f32 %0, %1, %2" : "=v"(c0[qn][m]) : "v"(p0), "v"(p1));
                    asm("v_cvt_pk_bf16_f32 %0, %1, %2" : "=v"(c1[qn][m]) : "v"(p2), "v"(p3));
                }
                li[qn] += rs;
            }
            // in-register transpose to PV B-fragments (permlane32 + permlane16)
#pragma unroll
            for (int qn = 0; qn < 2; ++qn)
#pragma unroll
                for (int ks = 0; ks < 2; ++ks) {
                    unsigned a0 = c0[qn][2 * ks], b0 = c0[qn][2 * ks + 1];
                    unsigned a1 = c1[qn][2 * ks], b1 = c1[qn][2 * ks + 1];
                    asm("v_permlane32_swap_b32 %0, %1" : "+v"(a0), "+v"(b0));
                    asm("v_permlane16_swap_b32 %0, %1" : "+v"(a0), "+v"(b0));
                    asm("v_permlane32_swap_b32 %0, %1" : "+v"(a1), "+v"(b1));
                    asm("v_permlane16_swap_b32 %0, %1" : "+v"(a1), "+v"(b1));
                    union { bf16x8 v; unsigned u[4]; } t8;
                    t8.u[0] = a0; t8.u[1] = a1; t8.u[2] = b0; t8.u[3] = b1;
                    pf[qn][h * 2 + ks] = t8.v;
                }
        }
        // ---- PV: 4 key-chunks x 4 d-blocks x 2 qn = 32 MFMA ----
#pragma unroll
        for (int nc = 0; nc < 4; ++nc) {
            const int row = nc * 16 + l16;
            const int rb = row * 128;
#pragma unroll
            for (int ks = 0; ks < 4; ++ks) {
                const bf16x8 vf =
                    *(const bf16x8*)&vT[buf][rb + (((ks * 4 + quad) ^ (row & 15)) * 8)];
#pragma unroll
                for (int qn = 0; qn < 2; ++qn)
                    accO[qn][nc] = __builtin_amdgcn_mfma_f32_16x16x32_bf16(vf, pf[qn][ks],
                                                                          accO[qn][nc],
                                                                          0, 0, 0);
            }
        }
    };

    stage(0, 0);
    __syncthreads();
    int cur = 0;
    for (int s = 0; s < steps; ++s) {
        if (s + 1 < steps) stage(s + 1, cur ^ 1);
        tile_step(cur, s);
        __syncthreads();
        cur ^= 1;
    }

#pragma unroll
    for (int qn = 0; qn < 2; ++qn) {
        li[qn] += __shfl_xor(li[qn], 16, 64);
        li[qn] += __shfl_xor(li[qn], 32, 64);
        const float inv = 1.0f / li[qn];
        const int npos = qbase + qn * 16 + l16;
#pragma unroll
        for (int nc = 0; nc < 4; ++nc) {
            bf16x4 ow;
#pragma unroll
            for (int r = 0; r < 4; ++r) ow[r] = f2bf(accO[qn][nc][r] * inv);
            *(bf16x4*)&og[(size_t)(bb * 2048 + npos) * 1024 + hh * 64 + nc * 16 + quad * 4] = ow;
        }
    }
}

// ---------------------------------------------------------------------------
// Launch  (4 dispatches: prep, gemm_qkv, attn, gemm_out)
// ---------------------------------------------------------------------------
extern "C" void kernel_launch(void* const* d_in, const int* in_sizes, int n_in,
                              void* d_out, int out_size, void* d_ws, size_t ws_size,
                              hipStream_t stream) {
    const float* x     = (const float*)d_in[0];
    const float* gamma = (const float*)d_in[1];
    const float* w_qkv = (const float*)d_in[2];
    const float* w_out = (const float*)d_in[3];
    float* out = (float*)d_out;
    char* ws = (char*)d_ws;

    short* xn     = (short*)(ws);                    //  8 MB
    short* wqkvT  = (short*)(ws + 8388608);          //  6 MB
    short* woutT  = (short*)(ws + 14680064);         //  2 MB
    short* q      = (short*)(ws + 16777216);         //  8 MB: [32][2048][64]
    short* k      = q + 32 * 2048 * 64;              //  8 MB: [32][2048][64]
    short* vt     = k + 32 * 2048 * 64;              //  8 MB: [32][64][2048]
    short* attn   = (short*)(ws + 41943040);         //  8 MB

    // prep: 768 (wqkv T) + 256 (wout T) + 4096 (rmsnorm) = 5120 blocks
    prep_kernel<<<5120, 256, 0, stream>>>(x, gamma, w_qkv, w_out, xn, wqkvT, woutT);
    // 128x192 tile, BK=64, 2 blocks/CU: 512 blocks, 256 threads
    gemm_qkv<<<512, 256, 0, stream>>>(xn, wqkvT, q, vt);
    // 512 blocks: (bh, 128-query tile), pair-balanced; KVBLK=128 steps
    attn_kernel<<<512, 256, 0, stream>>>(q, k, vt, attn);
    // 128x64 tile, BK=64 swizzled, 2-phase: 16x32 = 512 blocks
    gemm_out<<<dim3(16, 32), 256, 0, stream>>>(attn, woutT, out);
}